// Round 8
// baseline (45.776 us; speedup 1.0000x reference)
//
#include <hip/hip_runtime.h>

// Reference uses ONLY the last input channel (CIN-1) and matching weight slice:
// out[b,co,h,w] = bias[co] + sum_{kh,kw} x[b,63,h+kh,w+kw] * wt[co,63,kh,kw]
// out (64,64,112,112) f32 = 205.5 MB -> write-BW bound; pure-fill floor ~30us.
// History: R2 (NCO=4, direct loads, 1 out-row/thread) 39.65us BEST;
//   nt-stores neutral; NCO=8 42us; spatial-x4 81.6us; LDS staging 42.2us.
// This round: vertical ROW PAIR per thread -> 4 loaded rows serve 2 output
// rows (middle 2 rows reused), VMEM loads/output -40%, stores still 4 planes.

#define CB    64
#define CCIN  64
#define CCOUT 64
#define CH    112
#define CW    112
#define CHP   114
#define CWP   114
#define NCO   4
#define PPT   (56 * 28)       // 1568 (h-pair, wv) units per (b,co) plane

typedef float v4f __attribute__((ext_vector_type(4)));

__global__ __launch_bounds__(256) void CustomConv2D_12953621365171_kernel(
    const float* __restrict__ x,      // (B, CIN, 114, 114)
    const float* __restrict__ wt,     // (COUT, CIN, 3, 3)
    const float* __restrict__ bias,   // (COUT,)
    float* __restrict__ out)          // (B, COUT, 112, 112)
{
    int p = blockIdx.x * 256 + threadIdx.x;       // (h/2)*28 + wv
    if (p >= PPT) return;
    const int co0 = blockIdx.y * NCO;             // block-uniform -> SGPR
    const int b   = blockIdx.z;                   // block-uniform -> SGPR

    int hp = p / 28;                              // magic-mul div
    int wv = p - hp * 28;
    int h  = hp * 2;                              // even output row
    int w0 = wv * 4;

    // channel-63 x slice for this batch
    const float* xs = x + ((size_t)b * CCIN + (CCIN - 1)) * (CHP * CWP);

    // Load 4 input rows once; rows 1..2 are shared by both output rows.
    float r[4][6];
    #pragma unroll
    for (int kh = 0; kh < 4; ++kh) {
        const float* row = xs + (h + kh) * CWP + w0;
        __builtin_memcpy(&r[kh][0], row, 6 * sizeof(float));
    }

    #pragma unroll
    for (int j = 0; j < NCO; ++j) {
        // weights/bias: blockIdx-uniform -> scalar loads
        const float* wp = wt + ((size_t)(co0 + j) * CCIN + (CCIN - 1)) * 9;
        float bv = bias[co0 + j];
        float a0 = bv, a1 = bv, a2 = bv, a3 = bv;   // output row h
        float c0 = bv, c1 = bv, c2 = bv, c3 = bv;   // output row h+1
        #pragma unroll
        for (int kh = 0; kh < 3; ++kh) {
            float k0 = wp[kh * 3 + 0];
            float k1 = wp[kh * 3 + 1];
            float k2 = wp[kh * 3 + 2];
            float r0 = r[kh][0], r1 = r[kh][1], r2 = r[kh][2];
            float r3 = r[kh][3], r4 = r[kh][4], r5 = r[kh][5];
            a0 = fmaf(k0, r0, fmaf(k1, r1, fmaf(k2, r2, a0)));
            a1 = fmaf(k0, r1, fmaf(k1, r2, fmaf(k2, r3, a1)));
            a2 = fmaf(k0, r2, fmaf(k1, r3, fmaf(k2, r4, a2)));
            a3 = fmaf(k0, r3, fmaf(k1, r4, fmaf(k2, r5, a3)));
            float s0 = r[kh + 1][0], s1 = r[kh + 1][1], s2 = r[kh + 1][2];
            float s3 = r[kh + 1][3], s4 = r[kh + 1][4], s5 = r[kh + 1][5];
            c0 = fmaf(k0, s0, fmaf(k1, s1, fmaf(k2, s2, c0)));
            c1 = fmaf(k0, s1, fmaf(k1, s2, fmaf(k2, s3, c1)));
            c2 = fmaf(k0, s2, fmaf(k1, s3, fmaf(k2, s4, c2)));
            c3 = fmaf(k0, s3, fmaf(k1, s4, fmaf(k2, s5, c3)));
        }
        size_t off = ((size_t)b * CCOUT + (co0 + j)) * (CH * CW)
                   + (size_t)h * CW + w0;
        v4f oA = { a0, a1, a2, a3 };
        v4f oC = { c0, c1, c2, c3 };
        __builtin_nontemporal_store(oA, reinterpret_cast<v4f*>(out + off));
        __builtin_nontemporal_store(oC, reinterpret_cast<v4f*>(out + off + CW));
    }
}

extern "C" void kernel_launch(void* const* d_in, const int* in_sizes, int n_in,
                              void* d_out, int out_size, void* d_ws, size_t ws_size,
                              hipStream_t stream) {
    const float* x    = (const float*)d_in[0];
    const float* wt   = (const float*)d_in[1];
    const float* bias = (const float*)d_in[2];
    float* out = (float*)d_out;

    dim3 grid((PPT + 255) / 256,      // 7
              CCOUT / NCO,            // 16
              CB);                    // 64  -> 7168 blocks
    dim3 block(256, 1, 1);

    CustomConv2D_12953621365171_kernel<<<grid, block, 0, stream>>>(x, wt, bias, out);
}

// Round 9
// 39.623 us; speedup vs baseline: 1.1553x; 1.1553x over previous
//
#include <hip/hip_runtime.h>

// Reference uses ONLY the last input channel (CIN-1) and matching weight slice:
// out[b,co,h,w] = bias[co] + sum_{kh,kw} x[b,63,h+kh,w+kw] * wt[co,63,kh,kw]
// Shapes: x (64,64,114,114) f32, wt (64,64,3,3) f32, bias (64) f32,
//         out (64,64,112,112) f32 (205.5 MB) -> write-BW bound.
//
// MEASURED-BEST structure (R2, 39.65us = 5.2 TB/s effective, 75% of the
// harness fill kernel's 6.9 TB/s). All deviations regressed:
//   +nt stores / wide-load memcpy: neutral (39.78)
//   NCO=8 (8 planes/thread):       42.0  (store scatter)
//   4 contiguous spatial/thread:   81.6  (4x load insts)
//   LDS-staged reads:              42.2  (barrier + LDS latency)
//   vertical row-pair/thread:      45.8  (per-thread work growth)
// Max thread-level parallelism at 4 outputs/thread is the sweet spot.

#define CB    64
#define CCIN  64
#define CCOUT 64
#define CH    112
#define CW    112
#define CHP   114
#define CWP   114
#define NCO   4               // co values per thread (x-data reuse)
#define SPT   (CH * (CW/4))   // 3136 spatial float4-groups per (b,co) plane

__global__ __launch_bounds__(256) void CustomConv2D_12953621365171_kernel(
    const float* __restrict__ x,      // (B, CIN, 114, 114)
    const float* __restrict__ wt,     // (COUT, CIN, 3, 3)
    const float* __restrict__ bias,   // (COUT,)
    float* __restrict__ out)          // (B, COUT, 112, 112)
{
    int s = blockIdx.x * 256 + threadIdx.x;       // spatial: h*28 + wv
    if (s >= SPT) return;
    const int co0 = blockIdx.y * NCO;             // block-uniform -> SGPR
    const int b   = blockIdx.z;                   // block-uniform -> SGPR

    int h  = s / 28;                              // 32-bit magic-mul div
    int wv = s - h * 28;
    int w0 = wv * 4;

    // channel-63 x slice for this batch (uniform base + per-lane offset)
    const float* xs = x + ((size_t)b * CCIN + (CCIN - 1)) * (CHP * CWP);

    // Weights & bias: addresses depend only on blockIdx -> scalar loads
    float wk[NCO][9];
    float bv[NCO];
    #pragma unroll
    for (int j = 0; j < NCO; ++j) {
        const float* wp = wt + ((size_t)(co0 + j) * CCIN + (CCIN - 1)) * 9;
        #pragma unroll
        for (int t = 0; t < 9; ++t) wk[j][t] = wp[t];
        bv[j] = bias[co0 + j];
    }

    float acc[NCO][4];
    #pragma unroll
    for (int j = 0; j < NCO; ++j) {
        acc[j][0] = bv[j]; acc[j][1] = bv[j]; acc[j][2] = bv[j]; acc[j][3] = bv[j];
    }

    #pragma unroll
    for (int kh = 0; kh < 3; ++kh) {
        const float* row = xs + (h + kh) * CWP + w0;
        float r0 = row[0], r1 = row[1], r2 = row[2];
        float r3 = row[3], r4 = row[4], r5 = row[5];
        #pragma unroll
        for (int j = 0; j < NCO; ++j) {
            float k0 = wk[j][kh * 3 + 0];
            float k1 = wk[j][kh * 3 + 1];
            float k2 = wk[j][kh * 3 + 2];
            acc[j][0] = fmaf(k0, r0, fmaf(k1, r1, fmaf(k2, r2, acc[j][0])));
            acc[j][1] = fmaf(k0, r1, fmaf(k1, r2, fmaf(k2, r3, acc[j][1])));
            acc[j][2] = fmaf(k0, r2, fmaf(k1, r3, fmaf(k2, r4, acc[j][2])));
            acc[j][3] = fmaf(k0, r3, fmaf(k1, r4, fmaf(k2, r5, acc[j][3])));
        }
    }

    // out offset for (b, co0+j, h, w0) = plane*12544 + (h*112 + wv*4) = plane*12544 + s*4
    #pragma unroll
    for (int j = 0; j < NCO; ++j) {
        float4 o = make_float4(acc[j][0], acc[j][1], acc[j][2], acc[j][3]);
        size_t off = ((size_t)b * CCOUT + (co0 + j)) * (CH * CW) + (size_t)s * 4;
        *reinterpret_cast<float4*>(out + off) = o;
    }
}

extern "C" void kernel_launch(void* const* d_in, const int* in_sizes, int n_in,
                              void* d_out, int out_size, void* d_ws, size_t ws_size,
                              hipStream_t stream) {
    const float* x    = (const float*)d_in[0];
    const float* wt   = (const float*)d_in[1];
    const float* bias = (const float*)d_in[2];
    float* out = (float*)d_out;

    dim3 grid((SPT + 255) / 256,      // 13 blocks (last partially active)
              CCOUT / NCO,            // 16
              CB);                    // 64
    dim3 block(256, 1, 1);

    CustomConv2D_12953621365171_kernel<<<grid, block, 0, stream>>>(x, wt, bias, out);
}